// Round 1
// baseline (13144.403 us; speedup 1.0000x reference)
//
#include <hip/hip_runtime.h>

#define T_DIM 512
#define B_DIM 64
#define F_DIM 128
#define H_DIM 512

typedef _Float16 f16x8 __attribute__((ext_vector_type(8)));
typedef float f32x4 __attribute__((ext_vector_type(4)));

// ---------------------------------------------------------------------------
// prep: whT blocked [l][k/4][j][4] f32 (coalesced float4 per-column streaming)
// ---------------------------------------------------------------------------
__global__ void prep_whT(float* __restrict__ dst, const float* __restrict__ w0,
                         const float* __restrict__ w1, const float* __restrict__ w2) {
  const long total = 3L * 512 * 512;
  for (long idx = (long)blockIdx.x * blockDim.x + threadIdx.x; idx < total;
       idx += (long)gridDim.x * blockDim.x) {
    int l = (int)(idx >> 18);
    int rem = (int)(idx & 262143);
    int k = rem >> 9, j = rem & 511;
    const float* src = (l == 0) ? w0 : (l == 1) ? w1 : w2;
    dst[(long)l * 262144 + (long)(k >> 2) * 2048 + j * 4 + (k & 3)] = src[k * 512 + j];
  }
}

// ---------------------------------------------------------------------------
// prep: Wcat^T [l][n=512][kc=640] f16 ; kc<inK -> wi[kc][n], else ws[kc-inK][n]
// ---------------------------------------------------------------------------
__global__ void prep_wcat(_Float16* __restrict__ dst,
                          const float* __restrict__ wi0, const float* __restrict__ ws0,
                          const float* __restrict__ wi1, const float* __restrict__ ws1,
                          const float* __restrict__ wi2, const float* __restrict__ ws2) {
  const long total = 3L * 512 * 640;
  for (long idx = (long)blockIdx.x * blockDim.x + threadIdx.x; idx < total;
       idx += (long)gridDim.x * blockDim.x) {
    int l = (int)(idx / 327680);
    int rem = (int)(idx % 327680);
    int n = rem / 640, kc = rem % 640;
    int inK = (l == 0) ? 128 : 512;
    const float* wi = (l == 0) ? wi0 : (l == 1) ? wi1 : wi2;
    const float* ws = (l == 0) ? ws0 : (l == 1) ? ws1 : ws2;
    float v = 0.f;
    if (kc < inK) v = wi[kc * 512 + n];
    else if (kc < inK + 128) v = ws[(kc - inK) * 512 + n];
    dst[idx] = (_Float16)v;
  }
}

// ---------------------------------------------------------------------------
// build A' panel f16: row r=(t,b), cols [xs | sxs]; xs from inputs (l=0) or
// previous layer output (d_out slice); sxs = window-mean of x along t.
// ---------------------------------------------------------------------------
__global__ void build_A(_Float16* __restrict__ Abuf, const float* __restrict__ xin,
                        const float* __restrict__ prev, int n, int inK, int scale,
                        int layer) {
  const int Kcat = inK + 128;
  const long total = (long)n * 64 * Kcat;
  for (long idx = (long)blockIdx.x * blockDim.x + threadIdx.x; idx < total;
       idx += (long)gridDim.x * blockDim.x) {
    int k = (int)(idx % Kcat);
    long r = idx / Kcat;
    int b = (int)(r & 63);
    int t = (int)(r >> 6);
    float v;
    if (k < inK) {
      if (layer == 0) v = xin[((long)b * T_DIM + t) * F_DIM + k];
      else v = prev[((long)(t + scale - 1) * B_DIM + b) * H_DIM + k];
    } else {
      int kk = k - inK;
      int t0 = t + scale - 1;
      float s = 0.f;
      for (int w = 0; w < scale; ++w) s += xin[((long)b * T_DIM + t0 + w) * F_DIM + kk];
      v = s * (1.f / scale);
    }
    Abuf[idx] = (_Float16)v;
  }
}

// ---------------------------------------------------------------------------
// f16 MFMA GEMM: C[M][512] f32 = A[M][Kcat] f16 x Bt[512][640] f16 (row-major-K)
// BM=128 BN=128 BK=64, 256 thr (4 waves), wave = 64x64 quadrant of 16x16x32.
// ---------------------------------------------------------------------------
__global__ __launch_bounds__(256) void gemm_f16(const _Float16* __restrict__ A,
                                                const _Float16* __restrict__ Bt,
                                                float* __restrict__ C, int Mrows,
                                                int Kcat) {
  __shared__ _Float16 As[128][72];
  __shared__ _Float16 Bs[128][72];
  const int tid = threadIdx.x;
  const int tn = blockIdx.x, tm = blockIdx.y;
  const int lane = tid & 63, wid = tid >> 6;
  const int wm = wid >> 1, wn = wid & 1;
  f32x4 acc[4][4] = {};
  const int nK = Kcat >> 6;
  const int lrow = tid >> 3, lkc = (tid & 7) * 8;

  for (int kt = 0; kt < nK; ++kt) {
    for (int r = 0; r < 4; ++r) {
      int row = r * 32 + lrow;
      int grow = tm * 128 + row;
      uint4 va = make_uint4(0u, 0u, 0u, 0u);
      if (grow < Mrows) va = *(const uint4*)&A[(size_t)grow * Kcat + kt * 64 + lkc];
      *(uint4*)&As[row][lkc] = va;
      uint4 vb = *(const uint4*)&Bt[(size_t)(tn * 128 + row) * 640 + kt * 64 + lkc];
      *(uint4*)&Bs[row][lkc] = vb;
    }
    __syncthreads();
#pragma unroll
    for (int kk = 0; kk < 64; kk += 32) {
      f16x8 af[4], bf[4];
#pragma unroll
      for (int mt = 0; mt < 4; ++mt)
        af[mt] = *(const f16x8*)&As[wm * 64 + mt * 16 + (lane & 15)][kk + (lane >> 4) * 8];
#pragma unroll
      for (int nt = 0; nt < 4; ++nt)
        bf[nt] = *(const f16x8*)&Bs[wn * 64 + nt * 16 + (lane & 15)][kk + (lane >> 4) * 8];
#pragma unroll
      for (int mt = 0; mt < 4; ++mt)
#pragma unroll
        for (int nt = 0; nt < 4; ++nt)
          acc[mt][nt] = __builtin_amdgcn_mfma_f32_16x16x32_f16(af[mt], bf[nt], acc[mt][nt], 0, 0, 0);
    }
    __syncthreads();
  }

  const int crow0 = tm * 128 + wm * 64 + (lane >> 4) * 4;
  const int ccol0 = tn * 128 + wn * 64 + (lane & 15);
#pragma unroll
  for (int mt = 0; mt < 4; ++mt)
#pragma unroll
    for (int q = 0; q < 4; ++q) {
      int grow = crow0 + mt * 16 + q;
      if (grow < Mrows) {
#pragma unroll
        for (int nt = 0; nt < 4; ++nt)
          C[(size_t)grow * 512 + ccol0 + nt * 16] = acc[mt][nt][q];
      }
    }
}

// ---------------------------------------------------------------------------
// recurrence: one WG per batch. pre lives in d_out slice; overwritten in place
// with h_t. h broadcast via LDS; wh streamed f32 (blocked [k/4][j][4]).
// ---------------------------------------------------------------------------
__global__ __launch_bounds__(256) void rec_kernel(float* __restrict__ po,
                                                  const float4* __restrict__ wt, int n) {
  const int b = blockIdx.x, tid = threadIdx.x;
  __shared__ float hs[512];
  hs[tid] = 0.f;
  hs[tid + 256] = 0.f;
  __syncthreads();
  for (int t = 0; t < n; ++t) {
    float* row = po + (size_t)t * (B_DIM * H_DIM) + (size_t)b * H_DIM;
    float a0 = row[tid];
    float a1 = row[tid + 256];
#pragma unroll 4
    for (int k4 = 0; k4 < 128; ++k4) {
      const float4 h4 = *(const float4*)&hs[k4 * 4];
      const float4 wa = wt[k4 * 512 + tid];
      const float4 wb = wt[k4 * 512 + tid + 256];
      a0 += h4.x * wa.x + h4.y * wa.y + h4.z * wa.z + h4.w * wa.w;
      a1 += h4.x * wb.x + h4.y * wb.y + h4.z * wb.z + h4.w * wb.w;
    }
    float h0 = tanhf(a0), h1 = tanhf(a1);
    row[tid] = h0;
    row[tid + 256] = h1;
    __syncthreads();
    hs[tid] = h0;
    hs[tid + 256] = h1;
    __syncthreads();
  }
}

// ---------------------------------------------------------------------------
extern "C" void kernel_launch(void* const* d_in, const int* in_sizes, int n_in,
                              void* d_out, int out_size, void* d_ws, size_t ws_size,
                              hipStream_t stream) {
  const float* inputs = (const float*)d_in[0];
  const float* wi[3] = {(const float*)d_in[1], (const float*)d_in[4], (const float*)d_in[7]};
  const float* wsm[3] = {(const float*)d_in[2], (const float*)d_in[5], (const float*)d_in[8]};
  const float* wh[3] = {(const float*)d_in[3], (const float*)d_in[6], (const float*)d_in[9]};
  float* out = (float*)d_out;

  char* wsp = (char*)d_ws;
  float* whTb = (float*)wsp;                                   // 3*512*512*4   = 3,145,728 B
  _Float16* wcat = (_Float16*)(wsp + 3145728);                 // 3*512*640*2   = 1,966,080 B
  _Float16* Abuf = (_Float16*)(wsp + 5111808);                 // 32704*640*2   = 41,861,120 B

  prep_whT<<<1024, 256, 0, stream>>>(whTb, wh[0], wh[1], wh[2]);
  prep_wcat<<<1024, 256, 0, stream>>>(wcat, wi[0], wsm[0], wi[1], wsm[1], wi[2], wsm[2]);

  const int nL[3] = {511, 509, 505};
  const long offL[3] = {0L, 511L * 64 * 512, (511L + 509L) * 64 * 512};
  const int inKL[3] = {128, 512, 512};
  const int scaleL[3] = {1, 2, 4};

  for (int l = 0; l < 3; ++l) {
    const int n = nL[l], inK = inKL[l], Kcat = inK + 128;
    const float* prev = (l == 0) ? nullptr : out + offL[l - 1];
    build_A<<<4096, 256, 0, stream>>>(Abuf, inputs, prev, n, inK, scaleL[l], l);
    const int Mrows = n * 64;
    const int Mt = (Mrows + 127) / 128;
    gemm_f16<<<dim3(4, Mt), 256, 0, stream>>>(Abuf, wcat + (size_t)l * 512 * 640,
                                              out + offL[l], Mrows, Kcat);
    rec_kernel<<<64, 256, 0, stream>>>(out + offL[l],
                                       (const float4*)(whTb + (size_t)l * 262144), n);
  }
}

// Round 2
// 8174.259 us; speedup vs baseline: 1.6080x; 1.6080x over previous
//
#include <hip/hip_runtime.h>

#define T_DIM 512
#define B_DIM 64
#define F_DIM 128
#define H_DIM 512

typedef _Float16 f16x8 __attribute__((ext_vector_type(8)));
typedef float f32x4 __attribute__((ext_vector_type(4)));

// ---------------------------------------------------------------------------
// prep: whT16[l][j][k] f16  (wh[k][j] transposed, for B-fragment register loads)
// ---------------------------------------------------------------------------
__global__ void prep_whT16(_Float16* __restrict__ dst, const float* __restrict__ w0,
                           const float* __restrict__ w1, const float* __restrict__ w2) {
  const long total = 3L * 512 * 512;
  for (long idx = (long)blockIdx.x * blockDim.x + threadIdx.x; idx < total;
       idx += (long)gridDim.x * blockDim.x) {
    int l = (int)(idx >> 18);
    int rem = (int)(idx & 262143);
    int j = rem >> 9, k = rem & 511;
    const float* src = (l == 0) ? w0 : (l == 1) ? w1 : w2;
    dst[idx] = (_Float16)src[k * 512 + j];
  }
}

// ---------------------------------------------------------------------------
// prep: Wcat^T [l][n=512][kc=640] f16 (unchanged from R1)
// ---------------------------------------------------------------------------
__global__ void prep_wcat(_Float16* __restrict__ dst,
                          const float* __restrict__ wi0, const float* __restrict__ ws0,
                          const float* __restrict__ wi1, const float* __restrict__ ws1,
                          const float* __restrict__ wi2, const float* __restrict__ ws2) {
  const long total = 3L * 512 * 640;
  for (long idx = (long)blockIdx.x * blockDim.x + threadIdx.x; idx < total;
       idx += (long)gridDim.x * blockDim.x) {
    int l = (int)(idx / 327680);
    int rem = (int)(idx % 327680);
    int n = rem / 640, kc = rem % 640;
    int inK = (l == 0) ? 128 : 512;
    const float* wi = (l == 0) ? wi0 : (l == 1) ? wi1 : wi2;
    const float* ws = (l == 0) ? ws0 : (l == 1) ? ws1 : ws2;
    float v = 0.f;
    if (kc < inK) v = wi[kc * 512 + n];
    else if (kc < inK + 128) v = ws[(kc - inK) * 512 + n];
    dst[idx] = (_Float16)v;
  }
}

// ---------------------------------------------------------------------------
// build A' panel f16 (unchanged from R1)
// ---------------------------------------------------------------------------
__global__ void build_A(_Float16* __restrict__ Abuf, const float* __restrict__ xin,
                        const float* __restrict__ prev, int n, int inK, int scale,
                        int layer) {
  const int Kcat = inK + 128;
  const long total = (long)n * 64 * Kcat;
  for (long idx = (long)blockIdx.x * blockDim.x + threadIdx.x; idx < total;
       idx += (long)gridDim.x * blockDim.x) {
    int k = (int)(idx % Kcat);
    long r = idx / Kcat;
    int b = (int)(r & 63);
    int t = (int)(r >> 6);
    float v;
    if (k < inK) {
      if (layer == 0) v = xin[((long)b * T_DIM + t) * F_DIM + k];
      else v = prev[((long)(t + scale - 1) * B_DIM + b) * H_DIM + k];
    } else {
      int kk = k - inK;
      int t0 = t + scale - 1;
      float s = 0.f;
      for (int w = 0; w < scale; ++w) s += xin[((long)b * T_DIM + t0 + w) * F_DIM + kk];
      v = s * (1.f / scale);
    }
    Abuf[idx] = (_Float16)v;
  }
}

// ---------------------------------------------------------------------------
// f16 MFMA GEMM (unchanged from R1, verified)
// ---------------------------------------------------------------------------
__global__ __launch_bounds__(256) void gemm_f16(const _Float16* __restrict__ A,
                                                const _Float16* __restrict__ Bt,
                                                float* __restrict__ C, int Mrows,
                                                int Kcat) {
  __shared__ _Float16 As[128][72];
  __shared__ _Float16 Bs[128][72];
  const int tid = threadIdx.x;
  const int tn = blockIdx.x, tm = blockIdx.y;
  const int lane = tid & 63, wid = tid >> 6;
  const int wm = wid >> 1, wn = wid & 1;
  f32x4 acc[4][4] = {};
  const int nK = Kcat >> 6;
  const int lrow = tid >> 3, lkc = (tid & 7) * 8;

  for (int kt = 0; kt < nK; ++kt) {
    for (int r = 0; r < 4; ++r) {
      int row = r * 32 + lrow;
      int grow = tm * 128 + row;
      uint4 va = make_uint4(0u, 0u, 0u, 0u);
      if (grow < Mrows) va = *(const uint4*)&A[(size_t)grow * Kcat + kt * 64 + lkc];
      *(uint4*)&As[row][lkc] = va;
      uint4 vb = *(const uint4*)&Bt[(size_t)(tn * 128 + row) * 640 + kt * 64 + lkc];
      *(uint4*)&Bs[row][lkc] = vb;
    }
    __syncthreads();
#pragma unroll
    for (int kk = 0; kk < 64; kk += 32) {
      f16x8 af[4], bf[4];
#pragma unroll
      for (int mt = 0; mt < 4; ++mt)
        af[mt] = *(const f16x8*)&As[wm * 64 + mt * 16 + (lane & 15)][kk + (lane >> 4) * 8];
#pragma unroll
      for (int nt = 0; nt < 4; ++nt)
        bf[nt] = *(const f16x8*)&Bs[wn * 64 + nt * 16 + (lane & 15)][kk + (lane >> 4) * 8];
#pragma unroll
      for (int mt = 0; mt < 4; ++mt)
#pragma unroll
        for (int nt = 0; nt < 4; ++nt)
          acc[mt][nt] = __builtin_amdgcn_mfma_f32_16x16x32_f16(af[mt], bf[nt], acc[mt][nt], 0, 0, 0);
    }
    __syncthreads();
  }

  const int crow0 = tm * 128 + wm * 64 + (lane >> 4) * 4;
  const int ccol0 = tn * 128 + wn * 64 + (lane & 15);
#pragma unroll
  for (int mt = 0; mt < 4; ++mt)
#pragma unroll
    for (int q = 0; q < 4; ++q) {
      int grow = crow0 + mt * 16 + q;
      if (grow < Mrows) {
#pragma unroll
        for (int nt = 0; nt < 4; ++nt)
          C[(size_t)grow * 512 + ccol0 + nt * 16] = acc[mt][nt][q];
      }
    }
}

// ---------------------------------------------------------------------------
// zero the barrier counters (every launch — harness does not re-poison ws)
// ---------------------------------------------------------------------------
__global__ void zero_cnt(int* __restrict__ c, int ntot) {
  int i = blockIdx.x * blockDim.x + threadIdx.x;
  if (i < ntot) c[i] = 0;
}

// ---------------------------------------------------------------------------
// rec_mfma: persistent-weight MFMA recurrence.
// 16 WGs x 256 thr: group g = wg&3 owns batches [16g,16g+16); cslice = wg>>2
// owns cols [128*cs, 128*cs+128). B-frags (wh) live in 128 VGPRs per thread.
// Cross-WG exchange of h via global hbuf (f16) + per-step counters (fan-in 4).
// ---------------------------------------------------------------------------
__global__ __launch_bounds__(256) void rec_mfma(float* __restrict__ po,
                                                const _Float16* __restrict__ whT,
                                                _Float16* __restrict__ hbuf,
                                                int* __restrict__ cnt, int n) {
  const int tid = threadIdx.x;
  const int wg = blockIdx.x;
  const int g = wg & 3;
  const int cs = wg >> 2;
  const int lane = tid & 63, wid = tid >> 6;
  const int colbase = cs * 128 + wid * 32;
  const int b0 = g * 16;
  const int q_row = (lane >> 4) * 4;
  const int q_col = lane & 15;

  __shared__ _Float16 hstage[16 * 512];  // frag-order: uint4 idx = kb*64 + lane

  // --- load B fragments into registers (once) ---
  f16x8 bf[2][16];
  {
    const int jn0 = colbase + q_col;
    const int ko = (lane >> 4) * 8;
#pragma unroll
    for (int nt = 0; nt < 2; ++nt)
#pragma unroll
      for (int kb = 0; kb < 16; ++kb)
        bf[nt][kb] = *(const f16x8*)&whT[(size_t)(jn0 + nt * 16) * 512 + kb * 32 + ko];
  }

  _Float16* myh = hbuf + (size_t)g * 2 * (16 * 512);
  int* mycnt = cnt + g * 512;

  // staging-thread coords (frag-order gather: 16B per piece, 4 pieces)
  const int sl = tid & 63;
  const int skb0 = (tid >> 6) * 4;
  const int sgidx = (sl & 15) * 64 + (sl >> 4);  // uint4 idx base into [16][512] f16

  for (int t = 0; t < n; ++t) {
    // pre loads for this step — issued before the spin, latency hides under it
    float preg[2][4];
    {
      const float* pt = po + (size_t)t * (B_DIM * H_DIM);
#pragma unroll
      for (int nt = 0; nt < 2; ++nt)
#pragma unroll
        for (int q = 0; q < 4; ++q)
          preg[nt][q] =
              pt[(size_t)(b0 + q_row + q) * H_DIM + colbase + nt * 16 + q_col];
    }
    f32x4 acc[2];
#pragma unroll
    for (int nt = 0; nt < 2; ++nt) {
      acc[nt][0] = preg[nt][0];
      acc[nt][1] = preg[nt][1];
      acc[nt][2] = preg[nt][2];
      acc[nt][3] = preg[nt][3];
    }

    if (t > 0) {
      if (tid == 0) {
        int spins = 0;
        while (__hip_atomic_load(&mycnt[t - 1], __ATOMIC_ACQUIRE,
                                 __HIP_MEMORY_SCOPE_AGENT) < 4) {
          if (++spins > 40000000) break;
        }
      }
      __syncthreads();
      __threadfence();
      // stage group h_{t-1} (slot (t-1)&1) into frag-order LDS
      const uint4* hb4 = (const uint4*)(myh + ((t - 1) & 1) * (16 * 512));
      uint4* st4 = (uint4*)hstage;
#pragma unroll
      for (int p = 0; p < 4; ++p) {
        int kb = skb0 + p;
        st4[kb * 64 + sl] = hb4[sgidx + kb * 4];
      }
      __syncthreads();
#pragma unroll
      for (int kb = 0; kb < 16; ++kb) {
        f16x8 af = *(const f16x8*)&hstage[kb * 512 + lane * 8];
        acc[0] = __builtin_amdgcn_mfma_f32_16x16x32_f16(af, bf[0][kb], acc[0], 0, 0, 0);
        acc[1] = __builtin_amdgcn_mfma_f32_16x16x32_f16(af, bf[1][kb], acc[1], 0, 0, 0);
      }
      __syncthreads();  // hstage safe to overwrite next iter
    }

    // tanh + h16 write (critical path), f32 out write deferred past arrive
    float hv[2][4];
    _Float16* hw = myh + (t & 1) * (16 * 512);
#pragma unroll
    for (int nt = 0; nt < 2; ++nt)
#pragma unroll
      for (int q = 0; q < 4; ++q) {
        float a = acc[nt][q];
        float e = __expf(2.f * a);
        float h = 1.f - 2.f / (e + 1.f);
        hv[nt][q] = h;
        hw[(q_row + q) * 512 + colbase + nt * 16 + q_col] = (_Float16)h;
      }
    __threadfence();
    __syncthreads();
    if (tid == 0)
      __hip_atomic_fetch_add(&mycnt[t], 1, __ATOMIC_RELEASE, __HIP_MEMORY_SCOPE_AGENT);

    float* pt = po + (size_t)t * (B_DIM * H_DIM);
#pragma unroll
    for (int nt = 0; nt < 2; ++nt)
#pragma unroll
      for (int q = 0; q < 4; ++q)
        pt[(size_t)(b0 + q_row + q) * H_DIM + colbase + nt * 16 + q_col] = hv[nt][q];
  }
}

// ---------------------------------------------------------------------------
extern "C" void kernel_launch(void* const* d_in, const int* in_sizes, int n_in,
                              void* d_out, int out_size, void* d_ws, size_t ws_size,
                              hipStream_t stream) {
  const float* inputs = (const float*)d_in[0];
  const float* wi[3] = {(const float*)d_in[1], (const float*)d_in[4], (const float*)d_in[7]};
  const float* wsm[3] = {(const float*)d_in[2], (const float*)d_in[5], (const float*)d_in[8]};
  const float* wh[3] = {(const float*)d_in[3], (const float*)d_in[6], (const float*)d_in[9]};
  float* out = (float*)d_out;

  char* wsp = (char*)d_ws;
  _Float16* whT16 = (_Float16*)wsp;                       // 3*512*512*2 = 1,572,864
  _Float16* wcat = (_Float16*)(wsp + 1572864);            // 3*512*640*2 = 1,966,080
  int* cnt = (int*)(wsp + 3538944);                       // 3*4*512*4   = 24,576
  _Float16* hbuf = (_Float16*)(wsp + 3563520);            // 4*2*16*512*2 = 131,072
  _Float16* Abuf = (_Float16*)(wsp + 3694592);            // 32704*640*2 = 41,861,120

  zero_cnt<<<24, 256, 0, stream>>>(cnt, 3 * 4 * 512);
  prep_whT16<<<1024, 256, 0, stream>>>(whT16, wh[0], wh[1], wh[2]);
  prep_wcat<<<1024, 256, 0, stream>>>(wcat, wi[0], wsm[0], wi[1], wsm[1], wi[2], wsm[2]);

  const int nL[3] = {511, 509, 505};
  const long offL[3] = {0L, 511L * 64 * 512, (511L + 509L) * 64 * 512};
  const int inKL[3] = {128, 512, 512};
  const int scaleL[3] = {1, 2, 4};

  for (int l = 0; l < 3; ++l) {
    const int n = nL[l], inK = inKL[l], Kcat = inK + 128;
    const float* prev = (l == 0) ? nullptr : out + offL[l - 1];
    build_A<<<4096, 256, 0, stream>>>(Abuf, inputs, prev, n, inK, scaleL[l], l);
    const int Mrows = n * 64;
    const int Mt = (Mrows + 127) / 128;
    gemm_f16<<<dim3(4, Mt), 256, 0, stream>>>(Abuf, wcat + (size_t)l * 512 * 640,
                                              out + offL[l], Mrows, Kcat);
    rec_mfma<<<16, 256, 0, stream>>>(out + offL[l], whT16 + (size_t)l * 262144, hbuf,
                                     cnt + l * 4 * 512, n);
  }
}

// Round 3
// 6470.533 us; speedup vs baseline: 2.0314x; 1.2633x over previous
//
#include <hip/hip_runtime.h>

#define T_DIM 512
#define B_DIM 64
#define F_DIM 128
#define H_DIM 512

typedef _Float16 f16x8 __attribute__((ext_vector_type(8)));
typedef float f32x4 __attribute__((ext_vector_type(4)));

// ---------------------------------------------------------------------------
// prep: whT16[l][j][k] f16  (wh[k][j] transposed, for B-fragment loads)
// ---------------------------------------------------------------------------
__global__ void prep_whT16(_Float16* __restrict__ dst, const float* __restrict__ w0,
                           const float* __restrict__ w1, const float* __restrict__ w2) {
  const long total = 3L * 512 * 512;
  for (long idx = (long)blockIdx.x * blockDim.x + threadIdx.x; idx < total;
       idx += (long)gridDim.x * blockDim.x) {
    int l = (int)(idx >> 18);
    int rem = (int)(idx & 262143);
    int j = rem >> 9, k = rem & 511;
    const float* src = (l == 0) ? w0 : (l == 1) ? w1 : w2;
    dst[idx] = (_Float16)src[k * 512 + j];
  }
}

// ---------------------------------------------------------------------------
// prep: Wcat^T [l][n=512][kc=640] f16
// ---------------------------------------------------------------------------
__global__ void prep_wcat(_Float16* __restrict__ dst,
                          const float* __restrict__ wi0, const float* __restrict__ ws0,
                          const float* __restrict__ wi1, const float* __restrict__ ws1,
                          const float* __restrict__ wi2, const float* __restrict__ ws2) {
  const long total = 3L * 512 * 640;
  for (long idx = (long)blockIdx.x * blockDim.x + threadIdx.x; idx < total;
       idx += (long)gridDim.x * blockDim.x) {
    int l = (int)(idx / 327680);
    int rem = (int)(idx % 327680);
    int n = rem / 640, kc = rem % 640;
    int inK = (l == 0) ? 128 : 512;
    const float* wi = (l == 0) ? wi0 : (l == 1) ? wi1 : wi2;
    const float* ws = (l == 0) ? ws0 : (l == 1) ? ws1 : ws2;
    float v = 0.f;
    if (kc < inK) v = wi[kc * 512 + n];
    else if (kc < inK + 128) v = ws[(kc - inK) * 512 + n];
    dst[idx] = (_Float16)v;
  }
}

// ---------------------------------------------------------------------------
// build A' panel f16 (unchanged, verified)
// ---------------------------------------------------------------------------
__global__ void build_A(_Float16* __restrict__ Abuf, const float* __restrict__ xin,
                        const float* __restrict__ prev, int n, int inK, int scale,
                        int layer) {
  const int Kcat = inK + 128;
  const long total = (long)n * 64 * Kcat;
  for (long idx = (long)blockIdx.x * blockDim.x + threadIdx.x; idx < total;
       idx += (long)gridDim.x * blockDim.x) {
    int k = (int)(idx % Kcat);
    long r = idx / Kcat;
    int b = (int)(r & 63);
    int t = (int)(r >> 6);
    float v;
    if (k < inK) {
      if (layer == 0) v = xin[((long)b * T_DIM + t) * F_DIM + k];
      else v = prev[((long)(t + scale - 1) * B_DIM + b) * H_DIM + k];
    } else {
      int kk = k - inK;
      int t0 = t + scale - 1;
      float s = 0.f;
      for (int w = 0; w < scale; ++w) s += xin[((long)b * T_DIM + t0 + w) * F_DIM + kk];
      v = s * (1.f / scale);
    }
    Abuf[idx] = (_Float16)v;
  }
}

// ---------------------------------------------------------------------------
// f16 MFMA GEMM (unchanged, verified)
// ---------------------------------------------------------------------------
__global__ __launch_bounds__(256) void gemm_f16(const _Float16* __restrict__ A,
                                                const _Float16* __restrict__ Bt,
                                                float* __restrict__ C, int Mrows,
                                                int Kcat) {
  __shared__ _Float16 As[128][72];
  __shared__ _Float16 Bs[128][72];
  const int tid = threadIdx.x;
  const int tn = blockIdx.x, tm = blockIdx.y;
  const int lane = tid & 63, wid = tid >> 6;
  const int wm = wid >> 1, wn = wid & 1;
  f32x4 acc[4][4] = {};
  const int nK = Kcat >> 6;
  const int lrow = tid >> 3, lkc = (tid & 7) * 8;

  for (int kt = 0; kt < nK; ++kt) {
    for (int r = 0; r < 4; ++r) {
      int row = r * 32 + lrow;
      int grow = tm * 128 + row;
      uint4 va = make_uint4(0u, 0u, 0u, 0u);
      if (grow < Mrows) va = *(const uint4*)&A[(size_t)grow * Kcat + kt * 64 + lkc];
      *(uint4*)&As[row][lkc] = va;
      uint4 vb = *(const uint4*)&Bt[(size_t)(tn * 128 + row) * 640 + kt * 64 + lkc];
      *(uint4*)&Bs[row][lkc] = vb;
    }
    __syncthreads();
#pragma unroll
    for (int kk = 0; kk < 64; kk += 32) {
      f16x8 af[4], bf[4];
#pragma unroll
      for (int mt = 0; mt < 4; ++mt)
        af[mt] = *(const f16x8*)&As[wm * 64 + mt * 16 + (lane & 15)][kk + (lane >> 4) * 8];
#pragma unroll
      for (int nt = 0; nt < 4; ++nt)
        bf[nt] = *(const f16x8*)&Bs[wn * 64 + nt * 16 + (lane & 15)][kk + (lane >> 4) * 8];
#pragma unroll
      for (int mt = 0; mt < 4; ++mt)
#pragma unroll
        for (int nt = 0; nt < 4; ++nt)
          acc[mt][nt] = __builtin_amdgcn_mfma_f32_16x16x32_f16(af[mt], bf[nt], acc[mt][nt], 0, 0, 0);
    }
    __syncthreads();
  }

  const int crow0 = tm * 128 + wm * 64 + (lane >> 4) * 4;
  const int ccol0 = tn * 128 + wn * 64 + (lane & 15);
#pragma unroll
  for (int mt = 0; mt < 4; ++mt)
#pragma unroll
    for (int q = 0; q < 4; ++q) {
      int grow = crow0 + mt * 16 + q;
      if (grow < Mrows) {
#pragma unroll
        for (int nt = 0; nt < 4; ++nt)
          C[(size_t)grow * 512 + ccol0 + nt * 16] = acc[mt][nt][q];
      }
    }
}

// ---------------------------------------------------------------------------
// rec_fused: single-WG-per-batch-group recurrence. 4 WGs x 256 thr (4 waves,
// 1 wave/SIMD -> 512-VGPR budget). wh: kb 0..11 in VGPRs (bfr[8][12], 384
// regs), kb 12..15 in LDS (128 KB frag-order). h exchanged via LDS hstage
// (16 KB, A-frag order) with two intra-WG barriers per step. No global sync.
// ---------------------------------------------------------------------------
__global__ __launch_bounds__(256, 1) void rec_fused(float* __restrict__ po,
                                                    const _Float16* __restrict__ whT,
                                                    int n) {
  const int tid = threadIdx.x;
  const int b0 = blockIdx.x * 16;
  const int lane = tid & 63, wid = tid >> 6;
  const int colbase = wid * 128;  // wave owns cols [128w, 128w+128)
  const int q_col = lane & 15;
  const int q_row = (lane >> 4) * 4;

  __shared__ _Float16 hstage[16 * 512];        // 16 KB, A-frag order
  __shared__ _Float16 Blds[4 * 32 * 64 * 8];   // 128 KB, B-frag order kb 12..15

  // one-time: fill Blds (frag-order gather from whT)
  {
    uint4* B4 = (uint4*)Blds;
    for (int p = 0; p < 32; ++p) {
      int flat = p * 256 + tid;          // 0..8191
      int l = flat & 63;
      int gn = (flat >> 6) & 31;
      int kb12 = flat >> 11;             // 0..3
      B4[flat] = *(const uint4*)&whT[(size_t)(gn * 16 + (l & 15)) * 512 +
                                     (kb12 + 12) * 32 + (l >> 4) * 8];
    }
  }
  // one-time: B-frags kb 0..11 into registers (8 n-tiles x 12 kb = 384 VGPR)
  f16x8 bfr[8][12];
  {
    const int ko = (lane >> 4) * 8;
#pragma unroll
    for (int nt = 0; nt < 8; ++nt) {
      const int j = colbase + nt * 16 + q_col;
#pragma unroll
      for (int kb = 0; kb < 12; ++kb)
        bfr[nt][kb] = *(const f16x8*)&whT[(size_t)j * 512 + kb * 32 + ko];
    }
  }
  __syncthreads();  // Blds ready

  // global element (nt,q): po[t*32768 + (b0+q_row+q)*512 + colbase+nt*16+q_col]
  const size_t base = (size_t)(b0 + q_row) * 512 + colbase + q_col;

  // prefetch pre[0]
  float pf[8][4];
  {
    const float* p0 = po + base;
#pragma unroll
    for (int nt = 0; nt < 8; ++nt)
#pragma unroll
      for (int q = 0; q < 4; ++q) pf[nt][q] = p0[q * 512 + nt * 16];
  }

  for (int t = 0; t < n; ++t) {
    f32x4 acc[8];
#pragma unroll
    for (int nt = 0; nt < 8; ++nt) {
      acc[nt][0] = pf[nt][0];
      acc[nt][1] = pf[nt][1];
      acc[nt][2] = pf[nt][2];
      acc[nt][3] = pf[nt][3];
    }
    // prefetch pre[t+1] (latency hides under MFMA phase)
    {
      const int tnx = (t + 1 < n) ? t + 1 : t;
      const float* pn = po + (size_t)tnx * (B_DIM * H_DIM) + base;
#pragma unroll
      for (int nt = 0; nt < 8; ++nt)
#pragma unroll
        for (int q = 0; q < 4; ++q) pf[nt][q] = pn[q * 512 + nt * 16];
    }

    if (t > 0) {
      // kb 0..11: B from VGPR
#pragma unroll
      for (int kb = 0; kb < 12; ++kb) {
        f16x8 af = *(const f16x8*)&hstage[kb * 512 + lane * 8];
#pragma unroll
        for (int nt = 0; nt < 8; ++nt)
          acc[nt] = __builtin_amdgcn_mfma_f32_16x16x32_f16(af, bfr[nt][kb], acc[nt], 0, 0, 0);
      }
      // kb 12..15: B from LDS
#pragma unroll
      for (int kb = 12; kb < 16; ++kb) {
        f16x8 af = *(const f16x8*)&hstage[kb * 512 + lane * 8];
#pragma unroll
        for (int nt = 0; nt < 8; ++nt) {
          const int gn = (colbase >> 4) + nt;
          f16x8 bl = *(const f16x8*)&Blds[(((kb - 12) * 32 + gn) * 64 + lane) * 8];
          acc[nt] = __builtin_amdgcn_mfma_f32_16x16x32_f16(af, bl, acc[nt], 0, 0, 0);
        }
      }
    }
    __syncthreads();  // hstage reads of step t-1 complete

    // tanh in place; write h to hstage in A-frag order
#pragma unroll
    for (int nt = 0; nt < 8; ++nt) {
      const int j0 = colbase + nt * 16 + q_col;
      const int ha = (j0 >> 5) * 512 + ((j0 >> 3) & 3) * 128 + (j0 & 7);
#pragma unroll
      for (int q = 0; q < 4; ++q) {
        float a = acc[nt][q];
        float e = __expf(2.f * a);
        float h = 1.f - 2.f / (e + 1.f);
        acc[nt][q] = h;
        hstage[ha + (q_row + q) * 8] = (_Float16)h;
      }
    }
    __syncthreads();  // hstage writes complete

    // f32 output write (off critical path)
    float* pw = po + (size_t)t * (B_DIM * H_DIM) + base;
#pragma unroll
    for (int nt = 0; nt < 8; ++nt)
#pragma unroll
      for (int q = 0; q < 4; ++q) pw[q * 512 + nt * 16] = acc[nt][q];
  }
}

// ---------------------------------------------------------------------------
extern "C" void kernel_launch(void* const* d_in, const int* in_sizes, int n_in,
                              void* d_out, int out_size, void* d_ws, size_t ws_size,
                              hipStream_t stream) {
  const float* inputs = (const float*)d_in[0];
  const float* wi[3] = {(const float*)d_in[1], (const float*)d_in[4], (const float*)d_in[7]};
  const float* wsm[3] = {(const float*)d_in[2], (const float*)d_in[5], (const float*)d_in[8]};
  const float* wh[3] = {(const float*)d_in[3], (const float*)d_in[6], (const float*)d_in[9]};
  float* out = (float*)d_out;

  char* wsp = (char*)d_ws;
  _Float16* whT16 = (_Float16*)wsp;                 // 3*512*512*2 = 1,572,864
  _Float16* wcat = (_Float16*)(wsp + 1572864);      // 3*512*640*2 = 1,966,080
  _Float16* Abuf = (_Float16*)(wsp + 3538944);      // 32704*640*2 = 41,861,120

  prep_whT16<<<1024, 256, 0, stream>>>(whT16, wh[0], wh[1], wh[2]);
  prep_wcat<<<1024, 256, 0, stream>>>(wcat, wi[0], wsm[0], wi[1], wsm[1], wi[2], wsm[2]);

  const int nL[3] = {511, 509, 505};
  const long offL[3] = {0L, 511L * 64 * 512, (511L + 509L) * 64 * 512};
  const int inKL[3] = {128, 512, 512};
  const int scaleL[3] = {1, 2, 4};

  for (int l = 0; l < 3; ++l) {
    const int n = nL[l], inK = inKL[l], Kcat = inK + 128;
    const float* prev = (l == 0) ? nullptr : out + offL[l - 1];
    build_A<<<4096, 256, 0, stream>>>(Abuf, inputs, prev, n, inK, scaleL[l], l);
    const int Mrows = n * 64;
    const int Mt = (Mrows + 127) / 128;
    gemm_f16<<<dim3(4, Mt), 256, 0, stream>>>(Abuf, wcat + (size_t)l * 512 * 640,
                                              out + offL[l], Mrows, Kcat);
    rec_fused<<<4, 256, 0, stream>>>(out + offL[l], whT16 + (size_t)l * 262144, n);
  }
}